// Round 1
// baseline (369.657 us; speedup 1.0000x reference)
//
#include <hip/hip_runtime.h>
#include <math.h>

// Problem constants (from reference setup_inputs)
constexpr int B = 1024;   // batch
constexpr int A = 64;     // answers per query  (== one wavefront, by design)
constexpr int D = 1024;   // embedding dim
constexpr float EPS = 1e-8f;

__device__ __forceinline__ float wave_reduce_sum(float v) {
    #pragma unroll
    for (int off = 32; off > 0; off >>= 1) v += __shfl_xor(v, off, 64);
    return v;
}
__device__ __forceinline__ float wave_reduce_max(float v) {
    #pragma unroll
    for (int off = 32; off > 0; off >>= 1) v = fmaxf(v, __shfl_xor(v, off, 64));
    return v;
}

// One block per batch row b. 4 waves; wave w computes sims for answers
// [16w, 16w+16). Then wave 0 does softmax/KL/rank/DCG (A=64 == wave width).
__global__ __launch_bounds__(256) void rank_main(
    const float* __restrict__ q,       // [B, D]
    const float* __restrict__ emb,     // [B, A, D]
    const float* __restrict__ scores,  // [B, A]
    float* __restrict__ ws)            // [2*B]: kl_b, then ndcg_b
{
    const int b    = blockIdx.x;
    const int tid  = threadIdx.x;
    const int wave = tid >> 6;
    const int lane = tid & 63;

    __shared__ float sim_s[A];

    // q[b] register fragment: lane covers d = lane*4 + 256*it, it=0..3 (16 floats)
    const float4* q4 = reinterpret_cast<const float4*>(q + (size_t)b * D);
    const float4 qv0 = q4[lane];
    const float4 qv1 = q4[lane + 64];
    const float4 qv2 = q4[lane + 128];
    const float4 qv3 = q4[lane + 192];

    const int a0 = wave * 16;
    #pragma unroll 4
    for (int ai = 0; ai < 16; ++ai) {
        const int a = a0 + ai;
        const float4* e4 = reinterpret_cast<const float4*>(
            emb + ((size_t)b * A + a) * D);
        const float4 e0 = e4[lane];
        const float4 e1 = e4[lane + 64];
        const float4 e2 = e4[lane + 128];
        const float4 e3 = e4[lane + 192];
        float acc = qv0.x*e0.x + qv0.y*e0.y + qv0.z*e0.z + qv0.w*e0.w
                  + qv1.x*e1.x + qv1.y*e1.y + qv1.z*e1.z + qv1.w*e1.w
                  + qv2.x*e2.x + qv2.y*e2.y + qv2.z*e2.z + qv2.w*e2.w
                  + qv3.x*e3.x + qv3.y*e3.y + qv3.z*e3.z + qv3.w*e3.w;
        acc = wave_reduce_sum(acc);
        if (lane == 0) sim_s[a] = acc;
    }
    __syncthreads();

    if (tid >= 64) return;   // no further barriers — safe early exit

    const int a = lane;
    const float s  = sim_s[a];
    const float sc = scores[(size_t)b * A + a];

    // softmax over sim (TEMPERATURE == 1)
    const float m  = wave_reduce_max(s);
    const float ex = expf(s - m);              // underflows to 0 like numpy fp32
    const float se = wave_reduce_sum(ex);
    const float p  = ex / se;
    const float logp = logf(p + EPS);

    // target softmax over scores
    const float tm = wave_reduce_max(sc);
    const float te = expf(sc - tm);
    const float ts = wave_reduce_sum(te);
    const float t  = te / ts;
    const float logt = logf(t);

    const float kl = wave_reduce_sum(t * (logt - logp));

    // ranks: stable descending argsort == 1 + #{strictly greater} + #{equal with lower index}
    int rp = 1, ri = 1;
    #pragma unroll
    for (int r = 0; r < 64; ++r) {
        const float so = __shfl(s,  r, 64);
        const float co = __shfl(sc, r, 64);
        rp += (so > s)  || (so == s  && r < a);
        ri += (co > sc) || (co == sc && r < a);
    }

    // DCG: answer at rank r contributes score / log2(r+1)
    const float pd = wave_reduce_sum(sc / log2f((float)(rp + 1)));
    const float id = wave_reduce_sum(sc / log2f((float)(ri + 1)));

    if (lane == 0) {
        ws[b]     = kl;
        ws[B + b] = pd / (id + EPS);
    }
}

// Reduce 1024 per-row values -> 2 scalars: out[0]=mean(kl), out[1]=mean(ndcg)
__global__ __launch_bounds__(256) void rank_final(
    const float* __restrict__ ws, float* __restrict__ out)
{
    const int tid  = threadIdx.x;
    const int wave = tid >> 6;
    const int lane = tid & 63;
    __shared__ float sk[4], sn[4];

    float kl = 0.f, nd = 0.f;
    for (int i = tid; i < B; i += 256) {
        kl += ws[i];
        nd += ws[B + i];
    }
    kl = wave_reduce_sum(kl);
    nd = wave_reduce_sum(nd);
    if (lane == 0) { sk[wave] = kl; sn[wave] = nd; }
    __syncthreads();
    if (tid == 0) {
        const float K = sk[0] + sk[1] + sk[2] + sk[3];
        const float N = sn[0] + sn[1] + sn[2] + sn[3];
        out[0] = K * (1.0f / B);
        out[1] = N * (1.0f / B);
    }
}

extern "C" void kernel_launch(void* const* d_in, const int* in_sizes, int n_in,
                              void* d_out, int out_size, void* d_ws, size_t ws_size,
                              hipStream_t stream) {
    const float* q      = (const float*)d_in[0];  // [B, D]
    const float* emb    = (const float*)d_in[1];  // [B, A, D]
    const float* scores = (const float*)d_in[2];  // [B, A]
    float* out = (float*)d_out;                   // [2]: loss, avg_ndcg
    float* ws  = (float*)d_ws;                    // >= 2*B floats

    rank_main<<<B, 256, 0, stream>>>(q, emb, scores, ws);
    rank_final<<<1, 256, 0, stream>>>(ws, out);
}

// Round 2
// 368.663 us; speedup vs baseline: 1.0027x; 1.0027x over previous
//
#include <hip/hip_runtime.h>
#include <math.h>

// Problem constants (from reference setup_inputs)
constexpr int B = 1024;   // batch
constexpr int A = 64;     // answers per query (== one wavefront)
constexpr int D = 1024;   // embedding dim
constexpr float EPS = 1e-8f;

__device__ __forceinline__ float wave_reduce_sum(float v) {
    #pragma unroll
    for (int off = 32; off > 0; off >>= 1) v += __shfl_xor(v, off, 64);
    return v;
}
__device__ __forceinline__ float wave_reduce_max(float v) {
    #pragma unroll
    for (int off = 32; off > 0; off >>= 1) v = fmaxf(v, __shfl_xor(v, off, 64));
    return v;
}

// ---------------------------------------------------------------------------
// Kernel 1: similarity dots. Grid = 2*B blocks of 256 threads.
// Block (b, h): batch row b = blockIdx.x>>1, answer half h = blockIdx.x&1.
// Wave w handles answers [h*32 + 8w, h*32 + 8w + 8). No LDS, no barriers —
// reduced sims go straight to global scratch. __launch_bounds__(256,6)
// targets 6 blocks/CU (24 waves/CU) for latency hiding; VGPR cap 85.
// ---------------------------------------------------------------------------
__global__ __launch_bounds__(256, 6) void sim_kernel(
    const float* __restrict__ q,     // [B, D]
    const float* __restrict__ emb,   // [B, A, D]
    float* __restrict__ sims)        // [B, A] scratch
{
    const int b    = blockIdx.x >> 1;
    const int h    = blockIdx.x & 1;
    const int tid  = threadIdx.x;
    const int wave = tid >> 6;
    const int lane = tid & 63;

    // q[b] fragment: lane covers d = 4*lane + 256*it, it = 0..3 (16 floats)
    const float4* q4 = reinterpret_cast<const float4*>(q + (size_t)b * D);
    const float4 qv0 = q4[lane];
    const float4 qv1 = q4[lane + 64];
    const float4 qv2 = q4[lane + 128];
    const float4 qv3 = q4[lane + 192];

    const int a0 = h * 32 + wave * 8;
    #pragma unroll 2
    for (int ai = 0; ai < 8; ++ai) {
        const int a = a0 + ai;
        const float4* e4 = reinterpret_cast<const float4*>(
            emb + ((size_t)b * A + a) * D);
        const float4 e0 = e4[lane];
        const float4 e1 = e4[lane + 64];
        const float4 e2 = e4[lane + 128];
        const float4 e3 = e4[lane + 192];
        // 4 independent partial sums -> short dependence chains
        float s0 = qv0.x*e0.x + qv0.y*e0.y + qv0.z*e0.z + qv0.w*e0.w;
        float s1 = qv1.x*e1.x + qv1.y*e1.y + qv1.z*e1.z + qv1.w*e1.w;
        float s2 = qv2.x*e2.x + qv2.y*e2.y + qv2.z*e2.z + qv2.w*e2.w;
        float s3 = qv3.x*e3.x + qv3.y*e3.y + qv3.z*e3.z + qv3.w*e3.w;
        float acc = (s0 + s1) + (s2 + s3);
        acc = wave_reduce_sum(acc);
        if (lane == 0) sims[(size_t)b * A + a] = acc;
    }
}

// ---------------------------------------------------------------------------
// Kernel 2: per-row softmax / KL / ranks / DCG. One wave per batch row.
// Grid = B/4 blocks of 256 threads (wave w of block g handles row 4g+w).
// ---------------------------------------------------------------------------
__global__ __launch_bounds__(256) void loss_kernel(
    const float* __restrict__ sims,    // [B, A]
    const float* __restrict__ scores,  // [B, A]
    float* __restrict__ kl_out,        // [B]
    float* __restrict__ nd_out)        // [B]
{
    const int tid  = threadIdx.x;
    const int wave = tid >> 6;
    const int lane = tid & 63;
    const int r    = blockIdx.x * 4 + wave;

    const int a = lane;
    const float s  = sims[(size_t)r * A + a];
    const float sc = scores[(size_t)r * A + a];

    // softmax over sim (TEMPERATURE == 1)
    const float m  = wave_reduce_max(s);
    const float ex = expf(s - m);
    const float se = wave_reduce_sum(ex);
    const float p  = ex / se;
    const float logp = logf(p + EPS);

    // target softmax over scores
    const float tm = wave_reduce_max(sc);
    const float te = expf(sc - tm);
    const float ts = wave_reduce_sum(te);
    const float t  = te / ts;
    const float logt = logf(t);

    const float kl = wave_reduce_sum(t * (logt - logp));

    // stable descending ranks: 1 + #{greater} + #{equal with lower index}
    int rp = 1, ri = 1;
    #pragma unroll
    for (int o = 0; o < 64; ++o) {
        const float so = __shfl(s,  o, 64);
        const float co = __shfl(sc, o, 64);
        rp += (so > s)  || (so == s  && o < a);
        ri += (co > sc) || (co == sc && o < a);
    }

    const float pd = wave_reduce_sum(sc / log2f((float)(rp + 1)));
    const float id = wave_reduce_sum(sc / log2f((float)(ri + 1)));

    if (lane == 0) {
        kl_out[r] = kl;
        nd_out[r] = pd / (id + EPS);
    }
}

// ---------------------------------------------------------------------------
// Kernel 3: reduce B per-row values -> out[0]=mean(kl), out[1]=mean(ndcg)
// ---------------------------------------------------------------------------
__global__ __launch_bounds__(256) void final_kernel(
    const float* __restrict__ kl_in, const float* __restrict__ nd_in,
    float* __restrict__ out)
{
    const int tid  = threadIdx.x;
    const int wave = tid >> 6;
    const int lane = tid & 63;
    __shared__ float sk[4], sn[4];

    float kl = 0.f, nd = 0.f;
    for (int i = tid; i < B; i += 256) {
        kl += kl_in[i];
        nd += nd_in[i];
    }
    kl = wave_reduce_sum(kl);
    nd = wave_reduce_sum(nd);
    if (lane == 0) { sk[wave] = kl; sn[wave] = nd; }
    __syncthreads();
    if (tid == 0) {
        out[0] = (sk[0] + sk[1] + sk[2] + sk[3]) * (1.0f / B);
        out[1] = (sn[0] + sn[1] + sn[2] + sn[3]) * (1.0f / B);
    }
}

extern "C" void kernel_launch(void* const* d_in, const int* in_sizes, int n_in,
                              void* d_out, int out_size, void* d_ws, size_t ws_size,
                              hipStream_t stream) {
    const float* q      = (const float*)d_in[0];  // [B, D]
    const float* emb    = (const float*)d_in[1];  // [B, A, D]
    const float* scores = (const float*)d_in[2];  // [B, A]
    float* out = (float*)d_out;                   // [2]

    float* sims = (float*)d_ws;          // [B*A]
    float* kl_b = sims + (size_t)B * A;  // [B]
    float* nd_b = kl_b + B;              // [B]

    sim_kernel  <<<2 * B, 256, 0, stream>>>(q, emb, sims);
    loss_kernel <<<B / 4, 256, 0, stream>>>(sims, scores, kl_b, nd_b);
    final_kernel<<<1,     256, 0, stream>>>(kl_b, nd_b, out);
}